// Round 1
// baseline (457.990 us; speedup 1.0000x reference)
//
#include <hip/hip_runtime.h>

#define JB 24
#define NP 131072      // 2^17
#define CH 16
#define G  128

#define PLANE_ELEMS (JB*CH*G*G)   // 6,291,456 floats per plane array
#define LINE_ELEMS  (JB*CH*G)     // 49,152 floats per line array

// ---------------- transpose planes: (J,C,H,W) -> (J,H,W,C) ----------------
__global__ __launch_bounds__(256)
void transpose_planes_kernel(const float* __restrict__ p0,
                             const float* __restrict__ p1,
                             const float* __restrict__ p2,
                             float* __restrict__ wsp) {
    // one block per (plane, j, y) row: 3*24*128 = 9216 blocks
    __shared__ float lds[CH * (G + 1)];   // pad 129 to break bank conflicts
    int b = blockIdx.x;
    int y = b & (G - 1);
    int j = (b >> 7) % JB;
    int p = b / (G * JB);
    const float* src = (p == 0 ? p0 : (p == 1 ? p1 : p2))
                       + ((size_t)j * CH) * (G * G) + (size_t)y * G;
    float* dst = wsp + (size_t)p * PLANE_ELEMS + (((size_t)j * G + y) * G) * CH;
    int tid = threadIdx.x;
    // read coalesced: 16 channel rows of 128 floats
    for (int idx = tid; idx < G * CH; idx += 256) {
        int c = idx >> 7;          // 0..15
        int x = idx & (G - 1);
        lds[c * (G + 1) + x] = src[(size_t)c * G * G + x];
    }
    __syncthreads();
    // write coalesced: dst linear over (x,c)
    for (int idx = tid; idx < G * CH; idx += 256) {
        int x = idx >> 4;
        int c = idx & 15;
        dst[idx] = lds[c * (G + 1) + x];
    }
}

// ---------------- transpose lines: (J,C,L) -> (J,L,C) ----------------
__global__ __launch_bounds__(256)
void transpose_lines_kernel(const float* __restrict__ l0,
                            const float* __restrict__ l1,
                            const float* __restrict__ l2,
                            float* __restrict__ wsl) {
    int gid = blockIdx.x * 256 + threadIdx.x;   // over 3*LINE_ELEMS = 147456
    if (gid >= 3 * LINE_ELEMS) return;
    int p = gid / LINE_ELEMS;
    int r = gid % LINE_ELEMS;
    int c = r & 15;
    int z = (r >> 4) & (G - 1);
    int j = r >> 11;
    const float* src = (p == 0 ? l0 : (p == 1 ? l1 : l2));
    wsl[gid] = src[((size_t)j * CH + c) * G + z];
}

__device__ __forceinline__ float4 lerp4(float4 a, float4 b, float w) {
    float4 r;
    r.x = a.x + (b.x - a.x) * w;
    r.y = a.y + (b.y - a.y) * w;
    r.z = a.z + (b.z - a.z) * w;
    r.w = a.w + (b.w - a.w) * w;
    return r;
}

// ---------------- main fused kernel (transposed layout) ----------------
__global__ __launch_bounds__(256)
void tensorf_fused_kernel(const float* __restrict__ xyz,
                          const float* __restrict__ wsp,
                          const float* __restrict__ wsl,
                          float* __restrict__ out) {
    int gid = blockIdx.x * 256 + threadIdx.x;
    if (gid >= JB * NP) return;
    int j = gid >> 17;                       // NP = 2^17
    float cx = xyz[(size_t)gid * 3 + 0];
    float cy = xyz[(size_t)gid * 3 + 1];
    float cz = xyz[(size_t)gid * 3 + 2];
    const float co[3] = {cx, cy, cz};
    const int M0[3] = {0, 0, 1};
    const int M1[3] = {1, 2, 2};
    const int VZ[3] = {2, 1, 0};

    float4 acc4 = {0.f, 0.f, 0.f, 0.f};
    #pragma unroll
    for (int i = 0; i < 3; ++i) {
        float fx = (co[M0[i]] + 1.f) * 63.5f;
        float fy = (co[M1[i]] + 1.f) * 63.5f;
        float fz = (co[VZ[i]] + 1.f) * 63.5f;
        float f0x = fminf(fmaxf(floorf(fx), 0.f), 127.f);
        float f0y = fminf(fmaxf(floorf(fy), 0.f), 127.f);
        float f0z = fminf(fmaxf(floorf(fz), 0.f), 127.f);
        int x0 = (int)f0x, y0 = (int)f0y, z0 = (int)f0z;
        int x1 = min(x0 + 1, G - 1);
        int y1 = min(y0 + 1, G - 1);
        int z1 = min(z0 + 1, G - 1);
        float wx = fx - f0x, wy = fy - f0y, wz = fz - f0z;

        const float* pb = wsp + (size_t)i * PLANE_ELEMS + ((size_t)j * G * G) * CH;
        const float4* t00 = (const float4*)(pb + ((size_t)y0 * G + x0) * CH);
        const float4* t01 = (const float4*)(pb + ((size_t)y0 * G + x1) * CH);
        const float4* t10 = (const float4*)(pb + ((size_t)y1 * G + x0) * CH);
        const float4* t11 = (const float4*)(pb + ((size_t)y1 * G + x1) * CH);
        const float* lb = wsl + (size_t)i * LINE_ELEMS + ((size_t)j * G) * CH;
        const float4* l0 = (const float4*)(lb + (size_t)z0 * CH);
        const float4* l1 = (const float4*)(lb + (size_t)z1 * CH);

        #pragma unroll
        for (int q = 0; q < 4; ++q) {
            float4 v00 = t00[q], v01 = t01[q], v10 = t10[q], v11 = t11[q];
            float4 a0 = l0[q], a1 = l1[q];
            float4 top = lerp4(v00, v01, wx);
            float4 bot = lerp4(v10, v11, wx);
            float4 pv  = lerp4(top, bot, wy);
            float4 lv  = lerp4(a0, a1, wz);
            acc4.x += pv.x * lv.x;
            acc4.y += pv.y * lv.y;
            acc4.z += pv.z * lv.z;
            acc4.w += pv.w * lv.w;
        }
    }
    float acc = acc4.x + acc4.y + acc4.z + acc4.w;
    out[gid] = fmaxf(acc, 0.f);
}

// ---------------- fallback: direct layout (if ws too small) ----------------
__global__ __launch_bounds__(256)
void tensorf_direct_kernel(const float* __restrict__ xyz,
                           const float* __restrict__ p0,
                           const float* __restrict__ p1,
                           const float* __restrict__ p2,
                           const float* __restrict__ l0,
                           const float* __restrict__ l1,
                           const float* __restrict__ l2,
                           float* __restrict__ out) {
    int gid = blockIdx.x * 256 + threadIdx.x;
    if (gid >= JB * NP) return;
    int j = gid >> 17;
    float cx = xyz[(size_t)gid * 3 + 0];
    float cy = xyz[(size_t)gid * 3 + 1];
    float cz = xyz[(size_t)gid * 3 + 2];
    const float co[3] = {cx, cy, cz};
    const int M0[3] = {0, 0, 1};
    const int M1[3] = {1, 2, 2};
    const int VZ[3] = {2, 1, 0};
    const float* PP[3] = {p0, p1, p2};
    const float* LL[3] = {l0, l1, l2};

    float acc = 0.f;
    #pragma unroll
    for (int i = 0; i < 3; ++i) {
        float fx = (co[M0[i]] + 1.f) * 63.5f;
        float fy = (co[M1[i]] + 1.f) * 63.5f;
        float fz = (co[VZ[i]] + 1.f) * 63.5f;
        float f0x = fminf(fmaxf(floorf(fx), 0.f), 127.f);
        float f0y = fminf(fmaxf(floorf(fy), 0.f), 127.f);
        float f0z = fminf(fmaxf(floorf(fz), 0.f), 127.f);
        int x0 = (int)f0x, y0 = (int)f0y, z0 = (int)f0z;
        int x1 = min(x0 + 1, G - 1);
        int y1 = min(y0 + 1, G - 1);
        int z1 = min(z0 + 1, G - 1);
        float wx = fx - f0x, wy = fy - f0y, wz = fz - f0z;

        const float* p = PP[i] + (size_t)j * CH * G * G;
        const float* l = LL[i] + (size_t)j * CH * G;
        for (int c = 0; c < CH; ++c) {
            const float* pc = p + (size_t)c * G * G;
            float v00 = pc[(size_t)y0 * G + x0];
            float v01 = pc[(size_t)y0 * G + x1];
            float v10 = pc[(size_t)y1 * G + x0];
            float v11 = pc[(size_t)y1 * G + x1];
            float lc0 = l[(size_t)c * G + z0];
            float lc1 = l[(size_t)c * G + z1];
            float top = v00 + (v01 - v00) * wx;
            float bot = v10 + (v11 - v10) * wx;
            float pv  = top + (bot - top) * wy;
            float lv  = lc0 + (lc1 - lc0) * wz;
            acc += pv * lv;
        }
    }
    out[gid] = fmaxf(acc, 0.f);
}

extern "C" void kernel_launch(void* const* d_in, const int* in_sizes, int n_in,
                              void* d_out, int out_size, void* d_ws, size_t ws_size,
                              hipStream_t stream) {
    const float* xyz = (const float*)d_in[0];
    const float* p0  = (const float*)d_in[1];
    const float* l0  = (const float*)d_in[2];
    const float* p1  = (const float*)d_in[3];
    const float* l1  = (const float*)d_in[4];
    const float* p2  = (const float*)d_in[5];
    const float* l2  = (const float*)d_in[6];
    float* out = (float*)d_out;

    const size_t need = ((size_t)3 * PLANE_ELEMS + (size_t)3 * LINE_ELEMS) * sizeof(float);
    const int npts = JB * NP;
    const int nblocks = (npts + 255) / 256;

    if (ws_size >= need) {
        float* wsp = (float*)d_ws;
        float* wsl = wsp + (size_t)3 * PLANE_ELEMS;
        transpose_planes_kernel<<<3 * JB * G, 256, 0, stream>>>(p0, p1, p2, wsp);
        transpose_lines_kernel<<<(3 * LINE_ELEMS + 255) / 256, 256, 0, stream>>>(l0, l1, l2, wsl);
        tensorf_fused_kernel<<<nblocks, 256, 0, stream>>>(xyz, wsp, wsl, out);
    } else {
        tensorf_direct_kernel<<<nblocks, 256, 0, stream>>>(xyz, p0, p1, p2, l0, l1, l2, out);
    }
}

// Round 2
// 213.808 us; speedup vs baseline: 2.1421x; 2.1421x over previous
//
#include <hip/hip_runtime.h>

#define JB 24
#define NP 131072      // 2^17
#define CH 16
#define G  128

#define PLANE_ELEMS (JB*CH*G*G)   // 6,291,456 floats per plane array
#define LINE_ELEMS  (JB*CH*G)     // 49,152 floats per line array

// ---------------- transpose planes: (J,C,H,W) -> (J,H,W,C) ----------------
__global__ __launch_bounds__(256)
void transpose_planes_kernel(const float* __restrict__ p0,
                             const float* __restrict__ p1,
                             const float* __restrict__ p2,
                             float* __restrict__ wsp) {
    // one block per (plane, j, y) row: 3*24*128 = 9216 blocks
    __shared__ float lds[CH * (G + 1)];   // pad 129 to break bank conflicts
    int b = blockIdx.x;
    int y = b & (G - 1);
    int j = (b >> 7) % JB;
    int p = b / (G * JB);
    const float* src = (p == 0 ? p0 : (p == 1 ? p1 : p2))
                       + ((size_t)j * CH) * (G * G) + (size_t)y * G;
    float* dst = wsp + (size_t)p * PLANE_ELEMS + (((size_t)j * G + y) * G) * CH;
    int tid = threadIdx.x;
    for (int idx = tid; idx < G * CH; idx += 256) {
        int c = idx >> 7;          // 0..15
        int x = idx & (G - 1);
        lds[c * (G + 1) + x] = src[(size_t)c * G * G + x];
    }
    __syncthreads();
    for (int idx = tid; idx < G * CH; idx += 256) {
        int x = idx >> 4;
        int c = idx & 15;
        dst[idx] = lds[c * (G + 1) + x];
    }
}

// ---------------- transpose lines: (J,C,L) -> (J,L,C) ----------------
__global__ __launch_bounds__(256)
void transpose_lines_kernel(const float* __restrict__ l0,
                            const float* __restrict__ l1,
                            const float* __restrict__ l2,
                            float* __restrict__ wsl) {
    int gid = blockIdx.x * 256 + threadIdx.x;   // over 3*LINE_ELEMS = 147456
    if (gid >= 3 * LINE_ELEMS) return;
    int p = gid / LINE_ELEMS;
    int r = gid % LINE_ELEMS;
    int c = r & 15;
    int z = (r >> 4) & (G - 1);
    int j = r >> 11;
    const float* src = (p == 0 ? l0 : (p == 1 ? l1 : l2));
    wsl[gid] = src[((size_t)j * CH + c) * G + z];
}

__device__ __forceinline__ float4 lerp4(float4 a, float4 b, float w) {
    float4 r;
    r.x = a.x + (b.x - a.x) * w;
    r.y = a.y + (b.y - a.y) * w;
    r.z = a.z + (b.z - a.z) * w;
    r.w = a.w + (b.w - a.w) * w;
    return r;
}

// ---------------- main gather kernel: 4 lanes per point ----------------
// Lane group of 4 covers the 16 channels (float4 each). 18 float4 loads/lane.
__global__ __launch_bounds__(256)
void tensorf_gather4_kernel(const float* __restrict__ xyz,
                            const float* __restrict__ wsp,
                            const float* __restrict__ wsl,
                            float* __restrict__ out) {
    int gid = blockIdx.x * 256 + threadIdx.x;
    int pt = gid >> 2;                    // point index
    if (pt >= JB * NP) return;
    int l4 = gid & 3;                     // channel quad 0..3
    int j  = pt >> 17;                    // NP = 2^17

    float cx = xyz[(size_t)pt * 3 + 0];
    float cy = xyz[(size_t)pt * 3 + 1];
    float cz = xyz[(size_t)pt * 3 + 2];
    const float co[3] = {cx, cy, cz};
    const int M0[3] = {0, 0, 1};
    const int M1[3] = {1, 2, 2};
    const int VZ[3] = {2, 1, 0};

    float4 acc = {0.f, 0.f, 0.f, 0.f};
    #pragma unroll
    for (int i = 0; i < 3; ++i) {
        float fx = (co[M0[i]] + 1.f) * 63.5f;
        float fy = (co[M1[i]] + 1.f) * 63.5f;
        float fz = (co[VZ[i]] + 1.f) * 63.5f;
        float f0x = fminf(fmaxf(floorf(fx), 0.f), 126.f);
        float f0y = fminf(fmaxf(floorf(fy), 0.f), 126.f);
        float f0z = fminf(fmaxf(floorf(fz), 0.f), 126.f);
        int x0 = (int)f0x, y0 = (int)f0y, z0 = (int)f0z;
        float wx = fx - f0x, wy = fy - f0y, wz = fz - f0z;

        // plane base (floats): i*PLANE + (j<<18); tap offset ((y*128+x)<<4) + l4*4
        const float* pb = wsp + i * PLANE_ELEMS + (j << 18) + (l4 << 2);
        int o00 = ((y0 << 7) + x0) << 4;
        const float4 v00 = *(const float4*)(pb + o00);
        const float4 v01 = *(const float4*)(pb + o00 + CH);          // x0+1
        const float4 v10 = *(const float4*)(pb + o00 + (G << 4));    // y0+1
        const float4 v11 = *(const float4*)(pb + o00 + (G << 4) + CH);
        const float* lb = wsl + i * LINE_ELEMS + (j << 11) + (l4 << 2);
        const float4 a0 = *(const float4*)(lb + (z0 << 4));
        const float4 a1 = *(const float4*)(lb + (z0 << 4) + CH);     // z0+1

        float4 top = lerp4(v00, v01, wx);
        float4 bot = lerp4(v10, v11, wx);
        float4 pv  = lerp4(top, bot, wy);
        float4 lv  = lerp4(a0, a1, wz);
        acc.x += pv.x * lv.x;
        acc.y += pv.y * lv.y;
        acc.z += pv.z * lv.z;
        acc.w += pv.w * lv.w;
    }
    float s = acc.x + acc.y + acc.z + acc.w;
    s += __shfl_xor(s, 1);
    s += __shfl_xor(s, 2);
    if (l4 == 0) out[pt] = fmaxf(s, 0.f);
}

// ---------------- fallback: direct layout (if ws too small) ----------------
__global__ __launch_bounds__(256)
void tensorf_direct_kernel(const float* __restrict__ xyz,
                           const float* __restrict__ p0,
                           const float* __restrict__ p1,
                           const float* __restrict__ p2,
                           const float* __restrict__ l0,
                           const float* __restrict__ l1,
                           const float* __restrict__ l2,
                           float* __restrict__ out) {
    int gid = blockIdx.x * 256 + threadIdx.x;
    if (gid >= JB * NP) return;
    int j = gid >> 17;
    float cx = xyz[(size_t)gid * 3 + 0];
    float cy = xyz[(size_t)gid * 3 + 1];
    float cz = xyz[(size_t)gid * 3 + 2];
    const float co[3] = {cx, cy, cz};
    const int M0[3] = {0, 0, 1};
    const int M1[3] = {1, 2, 2};
    const int VZ[3] = {2, 1, 0};
    const float* PP[3] = {p0, p1, p2};
    const float* LL[3] = {l0, l1, l2};

    float acc = 0.f;
    #pragma unroll
    for (int i = 0; i < 3; ++i) {
        float fx = (co[M0[i]] + 1.f) * 63.5f;
        float fy = (co[M1[i]] + 1.f) * 63.5f;
        float fz = (co[VZ[i]] + 1.f) * 63.5f;
        float f0x = fminf(fmaxf(floorf(fx), 0.f), 127.f);
        float f0y = fminf(fmaxf(floorf(fy), 0.f), 127.f);
        float f0z = fminf(fmaxf(floorf(fz), 0.f), 127.f);
        int x0 = (int)f0x, y0 = (int)f0y, z0 = (int)f0z;
        int x1 = min(x0 + 1, G - 1);
        int y1 = min(y0 + 1, G - 1);
        int z1 = min(z0 + 1, G - 1);
        float wx = fx - f0x, wy = fy - f0y, wz = fz - f0z;

        const float* p = PP[i] + (size_t)j * CH * G * G;
        const float* l = LL[i] + (size_t)j * CH * G;
        for (int c = 0; c < CH; ++c) {
            const float* pc = p + (size_t)c * G * G;
            float v00 = pc[(size_t)y0 * G + x0];
            float v01 = pc[(size_t)y0 * G + x1];
            float v10 = pc[(size_t)y1 * G + x0];
            float v11 = pc[(size_t)y1 * G + x1];
            float lc0 = l[(size_t)c * G + z0];
            float lc1 = l[(size_t)c * G + z1];
            float top = v00 + (v01 - v00) * wx;
            float bot = v10 + (v11 - v10) * wx;
            float pv  = top + (bot - top) * wy;
            float lv  = lc0 + (lc1 - lc0) * wz;
            acc += pv * lv;
        }
    }
    out[gid] = fmaxf(acc, 0.f);
}

extern "C" void kernel_launch(void* const* d_in, const int* in_sizes, int n_in,
                              void* d_out, int out_size, void* d_ws, size_t ws_size,
                              hipStream_t stream) {
    const float* xyz = (const float*)d_in[0];
    const float* p0  = (const float*)d_in[1];
    const float* l0  = (const float*)d_in[2];
    const float* p1  = (const float*)d_in[3];
    const float* l1  = (const float*)d_in[4];
    const float* p2  = (const float*)d_in[5];
    const float* l2  = (const float*)d_in[6];
    float* out = (float*)d_out;

    const size_t need = ((size_t)3 * PLANE_ELEMS + (size_t)3 * LINE_ELEMS) * sizeof(float);
    const int npts = JB * NP;

    if (ws_size >= need) {
        float* wsp = (float*)d_ws;
        float* wsl = wsp + (size_t)3 * PLANE_ELEMS;
        transpose_planes_kernel<<<3 * JB * G, 256, 0, stream>>>(p0, p1, p2, wsp);
        transpose_lines_kernel<<<(3 * LINE_ELEMS + 255) / 256, 256, 0, stream>>>(l0, l1, l2, wsl);
        const int nthreads = npts * 4;
        tensorf_gather4_kernel<<<(nthreads + 255) / 256, 256, 0, stream>>>(xyz, wsp, wsl, out);
    } else {
        tensorf_direct_kernel<<<(npts + 255) / 256, 256, 0, stream>>>(xyz, p0, p1, p2, l0, l1, l2, out);
    }
}

// Round 3
// 172.993 us; speedup vs baseline: 2.6475x; 1.2359x over previous
//
#include <hip/hip_runtime.h>
#include <hip/hip_fp16.h>

#define JB 24
#define NP 131072      // 2^17
#define CH 16
#define G  128

#define PLANE_ELEMS (JB*CH*G*G)   // 6,291,456 elems per plane array
#define LINE_ELEMS  (JB*CH*G)     // 49,152 elems per line array

// ---------------- transpose planes: (J,C,H,W) fp32 -> (J,H,W,C) fp16 ----------------
__global__ __launch_bounds__(256)
void transpose_planes_kernel(const float* __restrict__ p0,
                             const float* __restrict__ p1,
                             const float* __restrict__ p2,
                             __half* __restrict__ wsp) {
    // one block per (plane, j, y) row: 3*24*128 = 9216 blocks
    __shared__ float lds[CH * (G + 1)];   // pad 129 to break bank conflicts
    int b = blockIdx.x;
    int y = b & (G - 1);
    int j = (b >> 7) % JB;
    int p = b / (G * JB);
    const float* src = (p == 0 ? p0 : (p == 1 ? p1 : p2))
                       + ((size_t)j * CH) * (G * G) + (size_t)y * G;
    __half* dst = wsp + (size_t)p * PLANE_ELEMS + (((size_t)j * G + y) * G) * CH;
    int tid = threadIdx.x;
    for (int idx = tid; idx < G * CH; idx += 256) {
        int c = idx >> 7;          // 0..15
        int x = idx & (G - 1);
        lds[c * (G + 1) + x] = src[(size_t)c * G * G + x];
    }
    __syncthreads();
    // write coalesced as __half2: 1024 half2 elems
    __half2* dst2 = (__half2*)dst;
    for (int idx = tid; idx < G * CH / 2; idx += 256) {
        int e0 = idx * 2;          // element pair (x,c) linear
        int x = e0 >> 4;
        int c0 = e0 & 15;
        float a = lds[c0 * (G + 1) + x];
        float bv = lds[(c0 + 1) * (G + 1) + x];
        dst2[idx] = __floats2half2_rn(a, bv);
    }
}

// ---------------- transpose lines: (J,C,L) fp32 -> (J,L,C) fp16 ----------------
__global__ __launch_bounds__(256)
void transpose_lines_kernel(const float* __restrict__ l0,
                            const float* __restrict__ l1,
                            const float* __restrict__ l2,
                            __half* __restrict__ wsl) {
    int gid = blockIdx.x * 256 + threadIdx.x;   // over 3*LINE_ELEMS = 147456
    if (gid >= 3 * LINE_ELEMS) return;
    int p = gid / LINE_ELEMS;
    int r = gid % LINE_ELEMS;
    int c = r & 15;
    int z = (r >> 4) & (G - 1);
    int j = r >> 11;
    const float* src = (p == 0 ? l0 : (p == 1 ? l1 : l2));
    wsl[gid] = __float2half(src[((size_t)j * CH + c) * G + z]);
}

__device__ __forceinline__ float4 lerp4(float4 a, float4 b, float w) {
    float4 r;
    r.x = a.x + (b.x - a.x) * w;
    r.y = a.y + (b.y - a.y) * w;
    r.z = a.z + (b.z - a.z) * w;
    r.w = a.w + (b.w - a.w) * w;
    return r;
}

__device__ __forceinline__ float4 h4_to_f4(uint2 u) {
    __half2 a = *(__half2*)&u.x;
    __half2 b = *(__half2*)&u.y;
    float2 fa = __half22float2(a);
    float2 fb = __half22float2(b);
    float4 r; r.x = fa.x; r.y = fa.y; r.z = fb.x; r.w = fb.y;
    return r;
}

// ---------------- main gather kernel: 4 lanes per point, fp16 taps ----------------
__global__ __launch_bounds__(256)
void tensorf_gather4h_kernel(const float* __restrict__ xyz,
                             const __half* __restrict__ wsp,
                             const __half* __restrict__ wsl,
                             float* __restrict__ out) {
    int gid = blockIdx.x * 256 + threadIdx.x;
    int pt = gid >> 2;                    // point index
    if (pt >= JB * NP) return;
    int l4 = gid & 3;                     // channel quad 0..3
    int j  = pt >> 17;                    // NP = 2^17

    float cx = xyz[(size_t)pt * 3 + 0];
    float cy = xyz[(size_t)pt * 3 + 1];
    float cz = xyz[(size_t)pt * 3 + 2];
    const float co[3] = {cx, cy, cz};
    const int M0[3] = {0, 0, 1};
    const int M1[3] = {1, 2, 2};
    const int VZ[3] = {2, 1, 0};

    float4 acc = {0.f, 0.f, 0.f, 0.f};
    #pragma unroll
    for (int i = 0; i < 3; ++i) {
        float fx = (co[M0[i]] + 1.f) * 63.5f;
        float fy = (co[M1[i]] + 1.f) * 63.5f;
        float fz = (co[VZ[i]] + 1.f) * 63.5f;
        float f0x = fminf(fmaxf(floorf(fx), 0.f), 126.f);
        float f0y = fminf(fmaxf(floorf(fy), 0.f), 126.f);
        float f0z = fminf(fmaxf(floorf(fz), 0.f), 126.f);
        int x0 = (int)f0x, y0 = (int)f0y, z0 = (int)f0z;
        float wx = fx - f0x, wy = fy - f0y, wz = fz - f0z;

        // element offsets identical to fp32 layout, 2B elems now
        const __half* pb = wsp + i * PLANE_ELEMS + (j << 18) + (l4 << 2);
        int o00 = ((y0 << 7) + x0) << 4;
        uint2 u00 = *(const uint2*)(pb + o00);
        uint2 u01 = *(const uint2*)(pb + o00 + CH);          // x0+1
        uint2 u10 = *(const uint2*)(pb + o00 + (G << 4));    // y0+1
        uint2 u11 = *(const uint2*)(pb + o00 + (G << 4) + CH);
        const __half* lb = wsl + i * LINE_ELEMS + (j << 11) + (l4 << 2);
        uint2 uz0 = *(const uint2*)(lb + (z0 << 4));
        uint2 uz1 = *(const uint2*)(lb + (z0 << 4) + CH);    // z0+1

        float4 v00 = h4_to_f4(u00), v01 = h4_to_f4(u01);
        float4 v10 = h4_to_f4(u10), v11 = h4_to_f4(u11);
        float4 a0  = h4_to_f4(uz0), a1  = h4_to_f4(uz1);

        float4 top = lerp4(v00, v01, wx);
        float4 bot = lerp4(v10, v11, wx);
        float4 pv  = lerp4(top, bot, wy);
        float4 lv  = lerp4(a0, a1, wz);
        acc.x += pv.x * lv.x;
        acc.y += pv.y * lv.y;
        acc.z += pv.z * lv.z;
        acc.w += pv.w * lv.w;
    }
    float s = acc.x + acc.y + acc.z + acc.w;
    s += __shfl_xor(s, 1);
    s += __shfl_xor(s, 2);
    if (l4 == 0) out[pt] = fmaxf(s, 0.f);
}

// ---------------- fallback: direct layout fp32 (if ws too small) ----------------
__global__ __launch_bounds__(256)
void tensorf_direct_kernel(const float* __restrict__ xyz,
                           const float* __restrict__ p0,
                           const float* __restrict__ p1,
                           const float* __restrict__ p2,
                           const float* __restrict__ l0,
                           const float* __restrict__ l1,
                           const float* __restrict__ l2,
                           float* __restrict__ out) {
    int gid = blockIdx.x * 256 + threadIdx.x;
    if (gid >= JB * NP) return;
    int j = gid >> 17;
    float cx = xyz[(size_t)gid * 3 + 0];
    float cy = xyz[(size_t)gid * 3 + 1];
    float cz = xyz[(size_t)gid * 3 + 2];
    const float co[3] = {cx, cy, cz};
    const int M0[3] = {0, 0, 1};
    const int M1[3] = {1, 2, 2};
    const int VZ[3] = {2, 1, 0};
    const float* PP[3] = {p0, p1, p2};
    const float* LL[3] = {l0, l1, l2};

    float acc = 0.f;
    #pragma unroll
    for (int i = 0; i < 3; ++i) {
        float fx = (co[M0[i]] + 1.f) * 63.5f;
        float fy = (co[M1[i]] + 1.f) * 63.5f;
        float fz = (co[VZ[i]] + 1.f) * 63.5f;
        float f0x = fminf(fmaxf(floorf(fx), 0.f), 127.f);
        float f0y = fminf(fmaxf(floorf(fy), 0.f), 127.f);
        float f0z = fminf(fmaxf(floorf(fz), 0.f), 127.f);
        int x0 = (int)f0x, y0 = (int)f0y, z0 = (int)f0z;
        int x1 = min(x0 + 1, G - 1);
        int y1 = min(y0 + 1, G - 1);
        int z1 = min(z0 + 1, G - 1);
        float wx = fx - f0x, wy = fy - f0y, wz = fz - f0z;

        const float* p = PP[i] + (size_t)j * CH * G * G;
        const float* l = LL[i] + (size_t)j * CH * G;
        for (int c = 0; c < CH; ++c) {
            const float* pc = p + (size_t)c * G * G;
            float v00 = pc[(size_t)y0 * G + x0];
            float v01 = pc[(size_t)y0 * G + x1];
            float v10 = pc[(size_t)y1 * G + x0];
            float v11 = pc[(size_t)y1 * G + x1];
            float lc0 = l[(size_t)c * G + z0];
            float lc1 = l[(size_t)c * G + z1];
            float top = v00 + (v01 - v00) * wx;
            float bot = v10 + (v11 - v10) * wx;
            float pv  = top + (bot - top) * wy;
            float lv  = lc0 + (lc1 - lc0) * wz;
            acc += pv * lv;
        }
    }
    out[gid] = fmaxf(acc, 0.f);
}

extern "C" void kernel_launch(void* const* d_in, const int* in_sizes, int n_in,
                              void* d_out, int out_size, void* d_ws, size_t ws_size,
                              hipStream_t stream) {
    const float* xyz = (const float*)d_in[0];
    const float* p0  = (const float*)d_in[1];
    const float* l0  = (const float*)d_in[2];
    const float* p1  = (const float*)d_in[3];
    const float* l1  = (const float*)d_in[4];
    const float* p2  = (const float*)d_in[5];
    const float* l2  = (const float*)d_in[6];
    float* out = (float*)d_out;

    const size_t need = ((size_t)3 * PLANE_ELEMS + (size_t)3 * LINE_ELEMS) * sizeof(__half);
    const int npts = JB * NP;

    if (ws_size >= need) {
        __half* wsp = (__half*)d_ws;
        __half* wsl = wsp + (size_t)3 * PLANE_ELEMS;
        transpose_planes_kernel<<<3 * JB * G, 256, 0, stream>>>(p0, p1, p2, wsp);
        transpose_lines_kernel<<<(3 * LINE_ELEMS + 255) / 256, 256, 0, stream>>>(l0, l1, l2, wsl);
        const int nthreads = npts * 4;
        tensorf_gather4h_kernel<<<(nthreads + 255) / 256, 256, 0, stream>>>(xyz, wsp, wsl, out);
    } else {
        tensorf_direct_kernel<<<(npts + 255) / 256, 256, 0, stream>>>(xyz, p0, p1, p2, l0, l1, l2, out);
    }
}

// Round 4
// 165.483 us; speedup vs baseline: 2.7676x; 1.0454x over previous
//
#include <hip/hip_runtime.h>
#include <hip/hip_fp16.h>
#include <stdint.h>

#define JB 24
#define NP 131072      // 2^17
#define CH 16
#define G  128

// workspace sizes in half2 units (1 half2 = 4 B)
#define PLANE_H2 (JB*G*G*CH)   // 6,291,456 half2 per plane array (25.2 MB)
#define LINE_H2  (JB*G*CH)     // 49,152 half2 per line array

typedef _Float16 h2_t __attribute__((ext_vector_type(2)));

__device__ __forceinline__ float fdot2(uint32_t a, h2_t w, float c) {
#if __has_builtin(__builtin_amdgcn_fdot2)
    return __builtin_amdgcn_fdot2(__builtin_bit_cast(h2_t, a), w, c, false);
#else
    __half2 ha = __builtin_bit_cast(__half2, a);
    float2 fa = __half22float2(ha);
    h2_t wv = w;
    return c + fa.x * (float)wv[0] + fa.y * (float)wv[1];
#endif
}

// ---- pack planes: (J,C,H,W) fp32 -> (plane,J,y,x,c) half2 pairs (v[x], v[x+1]) ----
__global__ __launch_bounds__(256)
void pack_planes_kernel(const float* __restrict__ p0,
                        const float* __restrict__ p1,
                        const float* __restrict__ p2,
                        __half2* __restrict__ wsp) {
    // one block per (plane, j, y) row: 3*24*128 = 9216 blocks
    __shared__ float lds[CH * (G + 1)];
    int b = blockIdx.x;
    int y = b & (G - 1);
    int j = (b >> 7) % JB;
    int p = b / (G * JB);
    const float* src = (p == 0 ? p0 : (p == 1 ? p1 : p2))
                       + ((size_t)j * CH) * (G * G) + (size_t)y * G;
    __half2* dst = wsp + ((size_t)(p * JB + j) * G + y) * (G * CH);
    int tid = threadIdx.x;
    for (int idx = tid; idx < G * CH; idx += 256) {
        int c = idx >> 7;          // 0..15
        int x = idx & (G - 1);
        lds[c * (G + 1) + x] = src[(size_t)c * G * G + x];
    }
    __syncthreads();
    // entry (x): 16 half2 of (v[x][c], v[x+1][c]); 2048 half2 per row
    for (int idx = tid; idx < G * CH; idx += 256) {
        int x = idx >> 4;
        int c = idx & 15;
        int x1 = (x < G - 1) ? x + 1 : x;
        float a = lds[c * (G + 1) + x];
        float bvv = lds[c * (G + 1) + x1];
        dst[idx] = __floats2half2_rn(a, bvv);
    }
}

// ---- pack lines: (J,C,L) fp32 -> (plane,J,z,c) half2 pairs (l[z], l[z+1]) ----
__global__ __launch_bounds__(256)
void pack_lines_kernel(const float* __restrict__ l0,
                       const float* __restrict__ l1,
                       const float* __restrict__ l2,
                       __half2* __restrict__ wsl) {
    int gid = blockIdx.x * 256 + threadIdx.x;   // over 3*LINE_H2 = 147456
    if (gid >= 3 * LINE_H2) return;
    int p = gid / LINE_H2;
    int r = gid - p * LINE_H2;
    int j = r >> 11;                 // G*CH = 2048
    int z = (r >> 4) & (G - 1);
    int c = r & 15;
    int z1 = (z < G - 1) ? z + 1 : z;
    const float* src = (p == 0 ? l0 : (p == 1 ? l1 : l2));
    float a = src[((size_t)j * CH + c) * G + z];
    float bvv = src[((size_t)j * CH + c) * G + z1];
    wsl[gid] = __floats2half2_rn(a, bvv);
}

// ---- main gather: 4 lanes/point, 3 aligned 64-B pair-loads per projection ----
__global__ __launch_bounds__(256)
void tensorf_pair_kernel(const float* __restrict__ xyz,
                         const uint32_t* __restrict__ wp,   // half2 units
                         const uint32_t* __restrict__ wl,   // half2 units
                         float* __restrict__ out) {
    int gid = blockIdx.x * 256 + threadIdx.x;
    int pt = gid >> 2;                    // point index
    if (pt >= JB * NP) return;
    int l4 = gid & 3;                     // channel quad 0..3 (ch 4*l4..4*l4+3)
    int j  = pt >> 17;                    // NP = 2^17

    float cx = xyz[(size_t)pt * 3 + 0];
    float cy = xyz[(size_t)pt * 3 + 1];
    float cz = xyz[(size_t)pt * 3 + 2];
    const float co[3] = {cx, cy, cz};
    const int M0[3] = {0, 0, 1};
    const int M1[3] = {1, 2, 2};
    const int VZ[3] = {2, 1, 0};

    float4 acc = {0.f, 0.f, 0.f, 0.f};
    #pragma unroll
    for (int i = 0; i < 3; ++i) {
        float fx = (co[M0[i]] + 1.f) * 63.5f;
        float fy = (co[M1[i]] + 1.f) * 63.5f;
        float fz = (co[VZ[i]] + 1.f) * 63.5f;
        float f0x = fminf(fmaxf(floorf(fx), 0.f), 126.f);
        float f0y = fminf(fmaxf(floorf(fy), 0.f), 126.f);
        float f0z = fminf(fmaxf(floorf(fz), 0.f), 126.f);
        int x0 = (int)f0x, y0 = (int)f0y, z0 = (int)f0z;
        float wx = fx - f0x, wy = fy - f0y, wz = fz - f0z;

        h2_t wxh = {(_Float16)(1.f - wx), (_Float16)wx};
        h2_t wzh = {(_Float16)(1.f - wz), (_Float16)wz};

        // plane entry base (half2 units): (i*24+j)*2^18 + (y0*128+x0)*16 + l4*4
        int pb = ((i * JB + j) << 18) + (((y0 << 7) + x0) << 4) + (l4 << 2);
        uint4 A = *(const uint4*)(wp + pb);              // row y0:   (v00,v01) pairs
        uint4 B = *(const uint4*)(wp + pb + (G << 4));   // row y0+1: (v10,v11) pairs
        int lb = ((i * JB + j) << 11) + (z0 << 4) + (l4 << 2);
        uint4 C = *(const uint4*)(wl + lb);              // (l[z0], l[z0+1]) pairs

        float t0 = fdot2(A.x, wxh, 0.f);
        float t1 = fdot2(A.y, wxh, 0.f);
        float t2 = fdot2(A.z, wxh, 0.f);
        float t3 = fdot2(A.w, wxh, 0.f);
        float b0 = fdot2(B.x, wxh, 0.f);
        float b1 = fdot2(B.y, wxh, 0.f);
        float b2 = fdot2(B.z, wxh, 0.f);
        float b3 = fdot2(B.w, wxh, 0.f);
        float v0 = fdot2(C.x, wzh, 0.f);
        float v1 = fdot2(C.y, wzh, 0.f);
        float v2 = fdot2(C.z, wzh, 0.f);
        float v3 = fdot2(C.w, wzh, 0.f);
        float p0 = t0 + (b0 - t0) * wy;
        float p1 = t1 + (b1 - t1) * wy;
        float p2 = t2 + (b2 - t2) * wy;
        float p3 = t3 + (b3 - t3) * wy;
        acc.x = fmaf(p0, v0, acc.x);
        acc.y = fmaf(p1, v1, acc.y);
        acc.z = fmaf(p2, v2, acc.z);
        acc.w = fmaf(p3, v3, acc.w);
    }
    float s = (acc.x + acc.y) + (acc.z + acc.w);
    s += __shfl_xor(s, 1);
    s += __shfl_xor(s, 2);
    if (l4 == 0) out[pt] = fmaxf(s, 0.f);
}

// ---------------- fallback: direct layout fp32 (if ws too small) ----------------
__global__ __launch_bounds__(256)
void tensorf_direct_kernel(const float* __restrict__ xyz,
                           const float* __restrict__ p0,
                           const float* __restrict__ p1,
                           const float* __restrict__ p2,
                           const float* __restrict__ l0,
                           const float* __restrict__ l1,
                           const float* __restrict__ l2,
                           float* __restrict__ out) {
    int gid = blockIdx.x * 256 + threadIdx.x;
    if (gid >= JB * NP) return;
    int j = gid >> 17;
    float cx = xyz[(size_t)gid * 3 + 0];
    float cy = xyz[(size_t)gid * 3 + 1];
    float cz = xyz[(size_t)gid * 3 + 2];
    const float co[3] = {cx, cy, cz};
    const int M0[3] = {0, 0, 1};
    const int M1[3] = {1, 2, 2};
    const int VZ[3] = {2, 1, 0};
    const float* PP[3] = {p0, p1, p2};
    const float* LL[3] = {l0, l1, l2};

    float acc = 0.f;
    #pragma unroll
    for (int i = 0; i < 3; ++i) {
        float fx = (co[M0[i]] + 1.f) * 63.5f;
        float fy = (co[M1[i]] + 1.f) * 63.5f;
        float fz = (co[VZ[i]] + 1.f) * 63.5f;
        float f0x = fminf(fmaxf(floorf(fx), 0.f), 127.f);
        float f0y = fminf(fmaxf(floorf(fy), 0.f), 127.f);
        float f0z = fminf(fmaxf(floorf(fz), 0.f), 127.f);
        int x0 = (int)f0x, y0 = (int)f0y, z0 = (int)f0z;
        int x1 = min(x0 + 1, G - 1);
        int y1 = min(y0 + 1, G - 1);
        int z1 = min(z0 + 1, G - 1);
        float wx = fx - f0x, wy = fy - f0y, wz = fz - f0z;

        const float* p = PP[i] + (size_t)j * CH * G * G;
        const float* l = LL[i] + (size_t)j * CH * G;
        for (int c = 0; c < CH; ++c) {
            const float* pc = p + (size_t)c * G * G;
            float v00 = pc[(size_t)y0 * G + x0];
            float v01 = pc[(size_t)y0 * G + x1];
            float v10 = pc[(size_t)y1 * G + x0];
            float v11 = pc[(size_t)y1 * G + x1];
            float lc0 = l[(size_t)c * G + z0];
            float lc1 = l[(size_t)c * G + z1];
            float top = v00 + (v01 - v00) * wx;
            float bot = v10 + (v11 - v10) * wx;
            float pv  = top + (bot - top) * wy;
            float lv  = lc0 + (lc1 - lc0) * wz;
            acc += pv * lv;
        }
    }
    out[gid] = fmaxf(acc, 0.f);
}

extern "C" void kernel_launch(void* const* d_in, const int* in_sizes, int n_in,
                              void* d_out, int out_size, void* d_ws, size_t ws_size,
                              hipStream_t stream) {
    const float* xyz = (const float*)d_in[0];
    const float* p0  = (const float*)d_in[1];
    const float* l0  = (const float*)d_in[2];
    const float* p1  = (const float*)d_in[3];
    const float* l1  = (const float*)d_in[4];
    const float* p2  = (const float*)d_in[5];
    const float* l2  = (const float*)d_in[6];
    float* out = (float*)d_out;

    const size_t need = ((size_t)3 * PLANE_H2 + (size_t)3 * LINE_H2) * sizeof(__half2);
    const int npts = JB * NP;

    if (ws_size >= need) {
        __half2* wsp = (__half2*)d_ws;
        __half2* wsl = wsp + (size_t)3 * PLANE_H2;
        pack_planes_kernel<<<3 * JB * G, 256, 0, stream>>>(p0, p1, p2, wsp);
        pack_lines_kernel<<<(3 * LINE_H2 + 255) / 256, 256, 0, stream>>>(l0, l1, l2, wsl);
        const int nthreads = npts * 4;
        tensorf_pair_kernel<<<(nthreads + 255) / 256, 256, 0, stream>>>(
            xyz, (const uint32_t*)wsp, (const uint32_t*)wsl, out);
    } else {
        tensorf_direct_kernel<<<(npts + 255) / 256, 256, 0, stream>>>(xyz, p0, p1, p2, l0, l1, l2, out);
    }
}

// Round 5
// 136.990 us; speedup vs baseline: 3.3432x; 1.2080x over previous
//
#include <hip/hip_runtime.h>
#include <hip/hip_fp16.h>
#include <stdint.h>

#define JB 24
#define NP 131072      // 2^17
#define CH 16
#define G  128

// workspace sizes in half2 units (1 half2 = 4 B)
#define PLANE_H2 (JB*G*G*CH)   // 6,291,456 half2 per plane array (25.2 MB)
#define LINE_H2  (JB*G*CH)     // 49,152 half2 per line array

typedef _Float16 h2_t __attribute__((ext_vector_type(2)));

__device__ __forceinline__ float fdot2(uint32_t a, h2_t w, float c) {
#if __has_builtin(__builtin_amdgcn_fdot2)
    return __builtin_amdgcn_fdot2(__builtin_bit_cast(h2_t, a), w, c, false);
#else
    __half2 ha = __builtin_bit_cast(__half2, a);
    float2 fa = __half22float2(ha);
    h2_t wv = w;
    return c + fa.x * (float)wv[0] + fa.y * (float)wv[1];
#endif
}

// ---- pack planes: (J,C,H,W) fp32 -> (plane,J,y,x,c) half2 pairs (v[x], v[x+1]) ----
__global__ __launch_bounds__(256)
void pack_planes_kernel(const float* __restrict__ p0,
                        const float* __restrict__ p1,
                        const float* __restrict__ p2,
                        __half2* __restrict__ wsp) {
    // one block per (plane, j, y) row: 3*24*128 = 9216 blocks
    __shared__ float lds[CH * (G + 1)];
    int b = blockIdx.x;
    int y = b & (G - 1);
    int j = (b >> 7) % JB;
    int p = b / (G * JB);
    const float* src = (p == 0 ? p0 : (p == 1 ? p1 : p2))
                       + ((size_t)j * CH) * (G * G) + (size_t)y * G;
    __half2* dst = wsp + ((size_t)(p * JB + j) * G + y) * (G * CH);
    int tid = threadIdx.x;
    for (int idx = tid; idx < G * CH; idx += 256) {
        int c = idx >> 7;          // 0..15
        int x = idx & (G - 1);
        lds[c * (G + 1) + x] = src[(size_t)c * G * G + x];
    }
    __syncthreads();
    // entry (x): 16 half2 of (v[x][c], v[x+1][c]); 2048 half2 per row
    for (int idx = tid; idx < G * CH; idx += 256) {
        int x = idx >> 4;
        int c = idx & 15;
        int x1 = (x < G - 1) ? x + 1 : x;
        float a = lds[c * (G + 1) + x];
        float bvv = lds[c * (G + 1) + x1];
        dst[idx] = __floats2half2_rn(a, bvv);
    }
}

// ---- pack lines: (J,C,L) fp32 -> (plane,J,z,c) half2 pairs (l[z], l[z+1]) ----
__global__ __launch_bounds__(256)
void pack_lines_kernel(const float* __restrict__ l0,
                       const float* __restrict__ l1,
                       const float* __restrict__ l2,
                       __half2* __restrict__ wsl) {
    int gid = blockIdx.x * 256 + threadIdx.x;   // over 3*LINE_H2 = 147456
    if (gid >= 3 * LINE_H2) return;
    int p = gid / LINE_H2;
    int r = gid - p * LINE_H2;
    int j = r >> 11;                 // G*CH = 2048
    int z = (r >> 4) & (G - 1);
    int c = r & 15;
    int z1 = (z < G - 1) ? z + 1 : z;
    const float* src = (p == 0 ? l0 : (p == 1 ? l1 : l2));
    float a = src[((size_t)j * CH + c) * G + z];
    float bvv = src[((size_t)j * CH + c) * G + z1];
    wsl[gid] = __floats2half2_rn(a, bvv);
}

// ---- main gather: 4 lanes/point, 3 aligned 64-B pair-loads per projection ----
// XCD-aware swizzle: each XCD (bid&7) owns a contiguous chunk of point-blocks,
// i.e. 3 whole j's processed sequentially -> per-j 3MiB plane set stays in its 4MiB L2.
__global__ __launch_bounds__(256)
void tensorf_pair_kernel(const float* __restrict__ xyz,
                         const uint32_t* __restrict__ wp,   // half2 units
                         const uint32_t* __restrict__ wl,   // half2 units
                         float* __restrict__ out) {
    int bid = blockIdx.x;
    int wg = (bid & 7) * ((JB * NP * 4 / 256) >> 3) + (bid >> 3);  // 6144 per XCD
    int gid = wg * 256 + threadIdx.x;
    int pt = gid >> 2;                    // point index
    if (pt >= JB * NP) return;
    int l4 = gid & 3;                     // channel quad 0..3 (ch 4*l4..4*l4+3)
    int j  = pt >> 17;                    // NP = 2^17

    float cx = xyz[(size_t)pt * 3 + 0];
    float cy = xyz[(size_t)pt * 3 + 1];
    float cz = xyz[(size_t)pt * 3 + 2];
    const float co[3] = {cx, cy, cz};
    const int M0[3] = {0, 0, 1};
    const int M1[3] = {1, 2, 2};
    const int VZ[3] = {2, 1, 0};

    float4 acc = {0.f, 0.f, 0.f, 0.f};
    #pragma unroll
    for (int i = 0; i < 3; ++i) {
        float fx = (co[M0[i]] + 1.f) * 63.5f;
        float fy = (co[M1[i]] + 1.f) * 63.5f;
        float fz = (co[VZ[i]] + 1.f) * 63.5f;
        float f0x = fminf(fmaxf(floorf(fx), 0.f), 126.f);
        float f0y = fminf(fmaxf(floorf(fy), 0.f), 126.f);
        float f0z = fminf(fmaxf(floorf(fz), 0.f), 126.f);
        int x0 = (int)f0x, y0 = (int)f0y, z0 = (int)f0z;
        float wx = fx - f0x, wy = fy - f0y, wz = fz - f0z;

        h2_t wxh = {(_Float16)(1.f - wx), (_Float16)wx};
        h2_t wzh = {(_Float16)(1.f - wz), (_Float16)wz};

        // plane entry base (half2 units): (i*24+j)*2^18 + (y0*128+x0)*16 + l4*4
        int pb = ((i * JB + j) << 18) + (((y0 << 7) + x0) << 4) + (l4 << 2);
        uint4 A = *(const uint4*)(wp + pb);              // row y0:   (v00,v01) pairs
        uint4 B = *(const uint4*)(wp + pb + (G << 4));   // row y0+1: (v10,v11) pairs
        int lb = ((i * JB + j) << 11) + (z0 << 4) + (l4 << 2);
        uint4 C = *(const uint4*)(wl + lb);              // (l[z0], l[z0+1]) pairs

        float t0 = fdot2(A.x, wxh, 0.f);
        float t1 = fdot2(A.y, wxh, 0.f);
        float t2 = fdot2(A.z, wxh, 0.f);
        float t3 = fdot2(A.w, wxh, 0.f);
        float b0 = fdot2(B.x, wxh, 0.f);
        float b1 = fdot2(B.y, wxh, 0.f);
        float b2 = fdot2(B.z, wxh, 0.f);
        float b3 = fdot2(B.w, wxh, 0.f);
        float v0 = fdot2(C.x, wzh, 0.f);
        float v1 = fdot2(C.y, wzh, 0.f);
        float v2 = fdot2(C.z, wzh, 0.f);
        float v3 = fdot2(C.w, wzh, 0.f);
        float p0 = t0 + (b0 - t0) * wy;
        float p1 = t1 + (b1 - t1) * wy;
        float p2 = t2 + (b2 - t2) * wy;
        float p3 = t3 + (b3 - t3) * wy;
        acc.x = fmaf(p0, v0, acc.x);
        acc.y = fmaf(p1, v1, acc.y);
        acc.z = fmaf(p2, v2, acc.z);
        acc.w = fmaf(p3, v3, acc.w);
    }
    float s = (acc.x + acc.y) + (acc.z + acc.w);
    s += __shfl_xor(s, 1);
    s += __shfl_xor(s, 2);
    if (l4 == 0) out[pt] = fmaxf(s, 0.f);
}

// ---------------- fallback: direct layout fp32 (if ws too small) ----------------
__global__ __launch_bounds__(256)
void tensorf_direct_kernel(const float* __restrict__ xyz,
                           const float* __restrict__ p0,
                           const float* __restrict__ p1,
                           const float* __restrict__ p2,
                           const float* __restrict__ l0,
                           const float* __restrict__ l1,
                           const float* __restrict__ l2,
                           float* __restrict__ out) {
    int gid = blockIdx.x * 256 + threadIdx.x;
    if (gid >= JB * NP) return;
    int j = gid >> 17;
    float cx = xyz[(size_t)gid * 3 + 0];
    float cy = xyz[(size_t)gid * 3 + 1];
    float cz = xyz[(size_t)gid * 3 + 2];
    const float co[3] = {cx, cy, cz};
    const int M0[3] = {0, 0, 1};
    const int M1[3] = {1, 2, 2};
    const int VZ[3] = {2, 1, 0};
    const float* PP[3] = {p0, p1, p2};
    const float* LL[3] = {l0, l1, l2};

    float acc = 0.f;
    #pragma unroll
    for (int i = 0; i < 3; ++i) {
        float fx = (co[M0[i]] + 1.f) * 63.5f;
        float fy = (co[M1[i]] + 1.f) * 63.5f;
        float fz = (co[VZ[i]] + 1.f) * 63.5f;
        float f0x = fminf(fmaxf(floorf(fx), 0.f), 127.f);
        float f0y = fminf(fmaxf(floorf(fy), 0.f), 127.f);
        float f0z = fminf(fmaxf(floorf(fz), 0.f), 127.f);
        int x0 = (int)f0x, y0 = (int)f0y, z0 = (int)f0z;
        int x1 = min(x0 + 1, G - 1);
        int y1 = min(y0 + 1, G - 1);
        int z1 = min(z0 + 1, G - 1);
        float wx = fx - f0x, wy = fy - f0y, wz = fz - f0z;

        const float* p = PP[i] + (size_t)j * CH * G * G;
        const float* l = LL[i] + (size_t)j * CH * G;
        for (int c = 0; c < CH; ++c) {
            const float* pc = p + (size_t)c * G * G;
            float v00 = pc[(size_t)y0 * G + x0];
            float v01 = pc[(size_t)y0 * G + x1];
            float v10 = pc[(size_t)y1 * G + x0];
            float v11 = pc[(size_t)y1 * G + x1];
            float lc0 = l[(size_t)c * G + z0];
            float lc1 = l[(size_t)c * G + z1];
            float top = v00 + (v01 - v00) * wx;
            float bot = v10 + (v11 - v10) * wx;
            float pv  = top + (bot - top) * wy;
            float lv  = lc0 + (lc1 - lc0) * wz;
            acc += pv * lv;
        }
    }
    out[gid] = fmaxf(acc, 0.f);
}

extern "C" void kernel_launch(void* const* d_in, const int* in_sizes, int n_in,
                              void* d_out, int out_size, void* d_ws, size_t ws_size,
                              hipStream_t stream) {
    const float* xyz = (const float*)d_in[0];
    const float* p0  = (const float*)d_in[1];
    const float* l0  = (const float*)d_in[2];
    const float* p1  = (const float*)d_in[3];
    const float* l1  = (const float*)d_in[4];
    const float* p2  = (const float*)d_in[5];
    const float* l2  = (const float*)d_in[6];
    float* out = (float*)d_out;

    const size_t need = ((size_t)3 * PLANE_H2 + (size_t)3 * LINE_H2) * sizeof(__half2);
    const int npts = JB * NP;

    if (ws_size >= need) {
        __half2* wsp = (__half2*)d_ws;
        __half2* wsl = wsp + (size_t)3 * PLANE_H2;
        pack_planes_kernel<<<3 * JB * G, 256, 0, stream>>>(p0, p1, p2, wsp);
        pack_lines_kernel<<<(3 * LINE_H2 + 255) / 256, 256, 0, stream>>>(l0, l1, l2, wsl);
        const int nthreads = npts * 4;   // 12,582,912 -> 49152 blocks (divisible by 8)
        tensorf_pair_kernel<<<(nthreads + 255) / 256, 256, 0, stream>>>(
            xyz, (const uint32_t*)wsp, (const uint32_t*)wsl, out);
    } else {
        tensorf_direct_kernel<<<(npts + 255) / 256, 256, 0, stream>>>(xyz, p0, p1, p2, l0, l1, l2, out);
    }
}